// Round 5
// baseline (510.707 us; speedup 1.0000x reference)
//
#include <hip/hip_runtime.h>
#include <cstdint>

// ---------------------------------------------------------------------------
// DirGraphSAGE round 13: source-bucket PHASED aggregation.
//  Theory shift (r12 evidence): agg rate is pinned at ~3.6 TB/s across MLP
//  depths x2/x4/x8 -> NOT latency-bound; it's L2-miss-byte-bound. Lever =
//  L2 temporal locality, i.e. fewer misses, not more in-flight loads.
//  - bucket(u) = u >> 13 (2MB slabs of xbu, 8 phases). Each CSR adjacency
//    list is sub-sorted by source bucket; k_agg6 processes buckets in order
//    with a __syncthreads() per bucket so all resident blocks (both dirs)
//    gather from the same 2MB slab at a time -> slab stays L2-resident.
//    Single pass: accumulators never leave registers (unlike the abandoned
//    multi-pass quartering - no acc round-trip, no ep re-reads).
//  - per-(node,bucket) ranks ride the SAME padded 64B counter lines
//    (8 slots/node) -> memset cost unchanged. k_compact packs 7x16b
//    intra-list prefixes into uint4/node. k_fill adds pre[bucket] lookup.
//  - x4 unroll within bucket (r12: VGPR>48 halves occupancy; x8 reverted).
//  - Everything else from r11: 4B payload (u<<16|deg), exact IEEE divide,
//    packed ranks, row-major bf16, split-W MFMA GEMM.
// ---------------------------------------------------------------------------

typedef __bf16 bf16x8 __attribute__((ext_vector_type(8)));
typedef float f32x4 __attribute__((ext_vector_type(4)));

__device__ __forceinline__ unsigned short f2bf(float f) {
  unsigned u = __float_as_uint(f);
  u += 0x7FFFu + ((u >> 16) & 1u);   // round-to-nearest-even
  return (unsigned short)(u >> 16);
}
__device__ __forceinline__ float bflo(unsigned u) { return __uint_as_float(u << 16); }
__device__ __forceinline__ float bfhi(unsigned u) { return __uint_as_float(u & 0xFFFF0000u); }

// prefix for bucket b (0..7) from packed uint4 (fields p1..p7); p0 = 0.
__device__ __forceinline__ unsigned prefield(uint4 v, int b) {
  if (b == 0) return 0u;
  int k = b - 1;  // 0..6
  unsigned w = (k < 2) ? v.x : (k < 4) ? v.y : (k < 6) ? v.z : v.w;
  return (k & 1) ? (w >> 16) : (w & 0xFFFFu);
}

// Padded counters: 16 ints (64B line) per node; slots 0..7 = per-bucket counts.
// Rank = arrival order within (node, source-bucket); packed 16|16 fwd|bwd.
__global__ __launch_bounds__(256) void k_degrees(const int* __restrict__ src,
                                                 const int* __restrict__ dst,
                                                 int* __restrict__ cin_p,
                                                 int* __restrict__ cout_p,
                                                 unsigned* __restrict__ rank_pk, int E) {
  int e = blockIdx.x * 256 + threadIdx.x;
  if (e >= E) return;
  int s = src[e], d = dst[e];
  int bf = (unsigned)s >> 13;   // bucket of gathered row for fwd list (by dst)
  int bb = (unsigned)d >> 13;   // bucket of gathered row for bwd list (by src)
  unsigned rf = (unsigned)atomicAdd(&cin_p[(size_t)d * 16 + bf], 1);
  unsigned rb = (unsigned)atomicAdd(&cout_p[(size_t)s * 16 + bb], 1);
  rank_pk[e] = (rf & 0xFFFFu) | (rb << 16);
}

// Per node: total degree (for scan) + packed 7x16b exclusive bucket prefixes.
__global__ __launch_bounds__(256) void k_compact(const int* __restrict__ cin_p,
                                                 const int* __restrict__ cout_p,
                                                 int* __restrict__ cin_d,
                                                 int* __restrict__ cout_d,
                                                 uint4* __restrict__ basef,
                                                 uint4* __restrict__ baseb, int n) {
  int i = blockIdx.x * 256 + threadIdx.x;
  if (i >= n) return;
  {
    const int* pf = &cin_p[(size_t)i * 16];
    int c0 = pf[0], c1 = pf[1], c2 = pf[2], c3 = pf[3];
    int c4 = pf[4], c5 = pf[5], c6 = pf[6], c7 = pf[7];
    unsigned run = c0;
    unsigned p1 = run; run += c1; unsigned p2 = run; run += c2;
    unsigned p3 = run; run += c3; unsigned p4 = run; run += c4;
    unsigned p5 = run; run += c5; unsigned p6 = run; run += c6;
    unsigned p7 = run; run += c7;
    cin_d[i] = (int)run;
    basef[i] = make_uint4(p1 | (p2 << 16), p3 | (p4 << 16), p5 | (p6 << 16), p7);
  }
  {
    const int* pf = &cout_p[(size_t)i * 16];
    int c0 = pf[0], c1 = pf[1], c2 = pf[2], c3 = pf[3];
    int c4 = pf[4], c5 = pf[5], c6 = pf[6], c7 = pf[7];
    unsigned run = c0;
    unsigned p1 = run; run += c1; unsigned p2 = run; run += c2;
    unsigned p3 = run; run += c3; unsigned p4 = run; run += c4;
    unsigned p5 = run; run += c5; unsigned p6 = run; run += c6;
    unsigned p7 = run; run += c7;
    cout_d[i] = (int)run;
    baseb[i] = make_uint4(p1 | (p2 << 16), p3 | (p4 << 16), p5 | (p6 << 16), p7);
  }
}

// --- 3-phase multi-block exclusive scan (CHUNK=2048/block, y-dim = which array)
__global__ __launch_bounds__(256) void k_scan_part(const int* __restrict__ cntA,
                                                   const int* __restrict__ cntB,
                                                   int* __restrict__ partA,
                                                   int* __restrict__ partB, int n) {
  const int* cnt = blockIdx.y ? cntB : cntA;
  int* part = blockIdx.y ? partB : partA;
  __shared__ int red[256];
  int t = threadIdx.x;
  int base = blockIdx.x * 2048 + t * 8;
  int s = 0;
#pragma unroll
  for (int i = 0; i < 8; ++i) {
    int idx = base + i;
    if (idx < n) s += cnt[idx];
  }
  red[t] = s;
  __syncthreads();
  for (int o = 128; o > 0; o >>= 1) {
    if (t < o) red[t] += red[t + o];
    __syncthreads();
  }
  if (t == 0) part[blockIdx.x] = red[0];
}

__global__ __launch_bounds__(64) void k_scan_tops(int* __restrict__ partA,
                                                  int* __restrict__ partB, int nb) {
  int* part = blockIdx.y ? partB : partA;
  if (threadIdx.x == 0) {
    int run = 0;
    for (int i = 0; i < nb; ++i) { int v = part[i]; part[i] = run; run += v; }
  }
}

__global__ __launch_bounds__(256) void k_scan_out(const int* __restrict__ cntA,
                                                  const int* __restrict__ cntB,
                                                  const int* __restrict__ partA,
                                                  const int* __restrict__ partB,
                                                  int* __restrict__ offA,
                                                  int* __restrict__ offB, int n) {
  const int* cnt = blockIdx.y ? cntB : cntA;
  const int* part = blockIdx.y ? partB : partA;
  int* off = blockIdx.y ? offB : offA;
  __shared__ int ts[256];
  int t = threadIdx.x;
  int base = blockIdx.x * 2048 + t * 8;
  int v[8];
  int s = 0;
#pragma unroll
  for (int i = 0; i < 8; ++i) {
    int idx = base + i;
    int c = (idx < n) ? cnt[idx] : 0;
    v[i] = s;          // exclusive prefix within thread
    s += c;
  }
  ts[t] = s;
  __syncthreads();
  for (int o = 1; o < 256; o <<= 1) {
    int val = (t >= o) ? ts[t - o] : 0;
    __syncthreads();
    ts[t] += val;
    __syncthreads();
  }
  int blockbase = part[blockIdx.x] + (t ? ts[t - 1] : 0);
#pragma unroll
  for (int i = 0; i < 8; ++i) {
    int idx = base + i;
    if (idx <= n) off[idx] = blockbase + v[i];   // idx==n writes the total
  }
}

// Atomic-free fill; pos = off[node] + bucketPrefix + rankWithinBucket.
__global__ __launch_bounds__(256) void k_fill(const int* __restrict__ src,
                                              const int* __restrict__ dst,
                                              const int* __restrict__ offf,
                                              const int* __restrict__ offb,
                                              const unsigned* __restrict__ rank_pk,
                                              const int* __restrict__ cout_d,
                                              const int* __restrict__ cin_d,
                                              const uint4* __restrict__ basef,
                                              const uint4* __restrict__ baseb,
                                              unsigned* __restrict__ epf,
                                              unsigned* __restrict__ epb, int E) {
  int e = blockIdx.x * 256 + threadIdx.x;
  if (e >= E) return;
  int s = src[e], d = dst[e];
  unsigned rp = rank_pk[e];
  int rf = (int)(rp & 0xFFFFu), rb = (int)(rp >> 16);
  int bf = (unsigned)s >> 13, bb = (unsigned)d >> 13;
  unsigned co = (unsigned)cout_d[s]; if (co > 65535u) co = 65535u;
  unsigned ci = (unsigned)cin_d[d];  if (ci > 65535u) ci = 65535u;
  epf[offf[d] + (int)prefield(basef[d], bf) + rf] = ((unsigned)s << 16) | co;
  epb[offb[s] + (int)prefield(baseb[s], bb) + rb] = ((unsigned)d << 16) | ci;
}

// x (fp32, N x 128) -> xbu row-major packed bf16x2 (32 uint2 per row)
__global__ __launch_bounds__(256) void k_conv(const float* __restrict__ x,
                                              unsigned* __restrict__ xbu, int n) {
  int idx = blockIdx.x * 256 + threadIdx.x;  // over n*32 float4s
  if (idx >= n * 32) return;
  float4 xv = ((const float4*)x)[idx];
  unsigned u0 = (unsigned)f2bf(xv.x) | ((unsigned)f2bf(xv.y) << 16);
  unsigned u1 = (unsigned)f2bf(xv.z) | ((unsigned)f2bf(xv.w) << 16);
  ((uint2*)xbu)[idx] = make_uint2(u0, u1);
}

// W (fp32 384x128) -> Wt_hi, Wt_lo (bf16, 128x384, transposed, packed x2)
__global__ __launch_bounds__(256) void k_wconv3(
    const float* __restrict__ Wa, const float* __restrict__ Wb,
    const float* __restrict__ Wc,
    unsigned* __restrict__ Ha, unsigned* __restrict__ Hb, unsigned* __restrict__ Hc,
    unsigned* __restrict__ La, unsigned* __restrict__ Lb, unsigned* __restrict__ Lc) {
  const float* W = (blockIdx.y == 0) ? Wa : ((blockIdx.y == 1) ? Wb : Wc);
  unsigned* Wth = (blockIdx.y == 0) ? Ha : ((blockIdx.y == 1) ? Hb : Hc);
  unsigned* Wtl = (blockIdx.y == 0) ? La : ((blockIdx.y == 1) ? Lb : Lc);
  int t = blockIdx.x * 256 + threadIdx.x;   // 128*192 threads; t = j*192 + k2
  if (t >= 128 * 192) return;
  int j = t / 192, k2 = t - j * 192;
  int k = k2 * 2;
  float w0 = W[k * 128 + j], w1 = W[(k + 1) * 128 + j];
  unsigned short h0 = f2bf(w0), h1 = f2bf(w1);
  float l0 = w0 - __uint_as_float((unsigned)h0 << 16);
  float l1 = w1 - __uint_as_float((unsigned)h1 << 16);
  Wth[t] = (unsigned)h0 | ((unsigned)h1 << 16);
  Wtl[t] = (unsigned)f2bf(l0) | ((unsigned)f2bf(l1) << 16);
}

// Phased row-major aggregation. 16 lanes/node, 4 nodes/wave. Buckets of the
// gathered id (2MB xbu slabs) processed in order with a block barrier per
// bucket: all resident blocks sweep the same slab -> slab stays L2-resident.
__global__ __launch_bounds__(256) void k_agg6(const uint4* __restrict__ xb,
                                              const int* __restrict__ offA,
                                              const unsigned* __restrict__ epA,
                                              const uint4* __restrict__ baseA,
                                              const int* __restrict__ offB,
                                              const unsigned* __restrict__ epB,
                                              const uint4* __restrict__ baseB,
                                              uint4* __restrict__ outA,
                                              uint4* __restrict__ outB, int n) {
  int lane = threadIdx.x & 63;
  int gi = lane >> 4, c = lane & 15;     // node-in-wave, uint4 column
  int node = ((blockIdx.x * 256 + threadIdx.x) >> 6) * 4 + gi;
  bool active = node < n;
  int nc = active ? node : 0;
  const int* off = blockIdx.y ? offB : offA;
  const unsigned* ep = blockIdx.y ? epB : epA;
  const uint4* basep = blockIdx.y ? baseB : baseA;
  uint4* out = blockIdx.y ? outB : outA;

  int i0 = off[nc];
  int deg = off[nc + 1] - i0;
  uint4 q = basep[nc];
  if (!active) { deg = 0; q = make_uint4(0u, 0u, 0u, 0u); }

  int pp[9];
  pp[0] = 0;
  pp[1] = (int)(q.x & 0xFFFFu); pp[2] = (int)(q.x >> 16);
  pp[3] = (int)(q.y & 0xFFFFu); pp[4] = (int)(q.y >> 16);
  pp[5] = (int)(q.z & 0xFFFFu); pp[6] = (int)(q.z >> 16);
  pp[7] = (int)(q.w & 0xFFFFu);
  pp[8] = deg;

  float acc[8];
#pragma unroll
  for (int k = 0; k < 8; ++k) acc[k] = 0.f;

#define AGG_BODY(r_, w_)                                                      \
  acc[0] = fmaf(bflo(r_.x), w_, acc[0]); acc[1] = fmaf(bfhi(r_.x), w_, acc[1]); \
  acc[2] = fmaf(bflo(r_.y), w_, acc[2]); acc[3] = fmaf(bfhi(r_.y), w_, acc[3]); \
  acc[4] = fmaf(bflo(r_.z), w_, acc[4]); acc[5] = fmaf(bfhi(r_.z), w_, acc[5]); \
  acc[6] = fmaf(bflo(r_.w), w_, acc[6]); acc[7] = fmaf(bfhi(r_.w), w_, acc[7]);

#pragma unroll
  for (int b = 0; b < 8; ++b) {
    int j = i0 + pp[b];
    int je = i0 + pp[b + 1];
    for (; j + 3 < je; j += 4) {
      unsigned e0 = ep[j], e1 = ep[j + 1], e2 = ep[j + 2], e3 = ep[j + 3];
      uint4 r0 = xb[(size_t)(e0 >> 16) * 16 + c];
      uint4 r1 = xb[(size_t)(e1 >> 16) * 16 + c];
      uint4 r2 = xb[(size_t)(e2 >> 16) * 16 + c];
      uint4 r3 = xb[(size_t)(e3 >> 16) * 16 + c];
      float w0 = 1.0f / (float)(e0 & 0xFFFFu);   // IEEE div: exact weight
      float w1 = 1.0f / (float)(e1 & 0xFFFFu);
      float w2 = 1.0f / (float)(e2 & 0xFFFFu);
      float w3 = 1.0f / (float)(e3 & 0xFFFFu);
      AGG_BODY(r0, w0)
      AGG_BODY(r1, w1)
      AGG_BODY(r2, w2)
      AGG_BODY(r3, w3)
    }
    for (; j < je; ++j) {
      unsigned e0 = ep[j];
      uint4 r0 = xb[(size_t)(e0 >> 16) * 16 + c];
      float w0 = 1.0f / (float)(e0 & 0xFFFFu);
      AGG_BODY(r0, w0)
    }
    __syncthreads();   // phase alignment: whole block moves to next slab
  }
#undef AGG_BODY

  if (active) {
    uint4 o;
    o.x = (unsigned)f2bf(acc[0]) | ((unsigned)f2bf(acc[1]) << 16);
    o.y = (unsigned)f2bf(acc[2]) | ((unsigned)f2bf(acc[3]) << 16);
    o.z = (unsigned)f2bf(acc[4]) | ((unsigned)f2bf(acc[5]) << 16);
    o.w = (unsigned)f2bf(acc[6]) | ((unsigned)f2bf(acc[7]) << 16);
    out[(size_t)node * 16 + c] = o;
  }
}

// MFMA GEMM: h = bias + [xbu|fwdb|bwdb][v,:] @ (W_hi + W_lo)   (row-major A)
// If outb: write bf16(relu(h)) row-major (next layer's xbu). Else fp32 outf.
__global__ __launch_bounds__(256) void k_gemm(const unsigned* __restrict__ xbu,
                                              const unsigned* __restrict__ fwdb,
                                              const unsigned* __restrict__ bwdb,
                                              const unsigned* __restrict__ Wth,
                                              const unsigned* __restrict__ Wtl,
                                              const float* __restrict__ bias,
                                              unsigned short* __restrict__ outb,
                                              float* __restrict__ outf, int n) {
  __shared__ uint4 sA[512];    // 8 KB: A chunk, frag order [mt][q][m]
  __shared__ uint4 sWh[512];   // 8 KB
  __shared__ uint4 sWl[512];   // 8 KB
  int tid = threadIdx.x;
  int bm0 = blockIdx.x * 128;
  int w = tid >> 6, lane = tid & 63;

  f32x4 acc[2][8];
#pragma unroll
  for (int mt = 0; mt < 2; ++mt)
#pragma unroll
    for (int nt = 0; nt < 8; ++nt) acc[mt][nt] = (f32x4){0.f, 0.f, 0.f, 0.f};

  const uint4* Wh4 = (const uint4*)Wth;   // row j: 48 uint4 (384 bf16)
  const uint4* Wl4 = (const uint4*)Wtl;

  for (int kc = 0; kc < 12; ++kc) {
    const uint4* src4 = (const uint4*)((kc < 4) ? xbu : ((kc < 8) ? fwdb : bwdb));
    int ko = (kc & 3) * 4;   // uint4 offset within row (16 uint4 = 128 bf16)
    __syncthreads();
#pragma unroll
    for (int p = 0; p < 2; ++p) {
      int f = tid + p * 256;          // 0..511
      int r = f >> 2, q = f & 3;      // r: row/col-of-W, q: k-quad
      int slot = (r >> 4) * 64 + q * 16 + (r & 15);
      int v = bm0 + r;
      uint4 val = make_uint4(0u, 0u, 0u, 0u);
      if (v < n) val = src4[(size_t)v * 16 + ko + q];
      sA[slot] = val;
      sWh[slot] = Wh4[(size_t)r * 48 + kc * 4 + q];
      sWl[slot] = Wl4[(size_t)r * 48 + kc * 4 + q];
    }
    __syncthreads();
    bf16x8 a0 = ((const bf16x8*)sA)[(2 * w) * 64 + lane];
    bf16x8 a1 = ((const bf16x8*)sA)[(2 * w + 1) * 64 + lane];
#pragma unroll
    for (int nt = 0; nt < 8; ++nt) {
      bf16x8 bh = ((const bf16x8*)sWh)[nt * 64 + lane];
      bf16x8 bl = ((const bf16x8*)sWl)[nt * 64 + lane];
      acc[0][nt] = __builtin_amdgcn_mfma_f32_16x16x32_bf16(a0, bh, acc[0][nt], 0, 0, 0);
      acc[0][nt] = __builtin_amdgcn_mfma_f32_16x16x32_bf16(a0, bl, acc[0][nt], 0, 0, 0);
      acc[1][nt] = __builtin_amdgcn_mfma_f32_16x16x32_bf16(a1, bh, acc[1][nt], 0, 0, 0);
      acc[1][nt] = __builtin_amdgcn_mfma_f32_16x16x32_bf16(a1, bl, acc[1][nt], 0, 0, 0);
    }
  }

  // Epilogue. C layout: col = lane&15, row = (lane>>4)*4 + reg  (m89-verified)
  int col = lane & 15;
  float bv[8];
#pragma unroll
  for (int nt = 0; nt < 8; ++nt) bv[nt] = bias[nt * 16 + col];
#pragma unroll
  for (int mt = 0; mt < 2; ++mt) {
    int rowbase = bm0 + w * 32 + mt * 16 + (lane >> 4) * 4;
#pragma unroll
    for (int reg = 0; reg < 4; ++reg) {
      int row = rowbase + reg;
      if (row >= n) continue;
      if (outb) {
#pragma unroll
        for (int nt = 0; nt < 8; ++nt) {
          float t = fmaxf(acc[mt][nt][reg] + bv[nt], 0.f);   // relu layers
          outb[(size_t)row * 128 + nt * 16 + col] = f2bf(t);
        }
      } else {
#pragma unroll
        for (int nt = 0; nt < 8; ++nt) {
          float t = acc[mt][nt][reg] + bv[nt];
          outf[(size_t)row * 128 + nt * 16 + col] = t;
        }
      }
    }
  }
}

extern "C" void kernel_launch(void* const* d_in, const int* in_sizes, int n_in,
                              void* d_out, int out_size, void* d_ws, size_t ws_size,
                              hipStream_t stream) {
  const int D = 128;
  const int N = in_sizes[0] / D;
  const int E = in_sizes[7];

  const float* x  = (const float*)d_in[0];
  const float* W0 = (const float*)d_in[1];
  const float* b0 = (const float*)d_in[2];
  const float* W1 = (const float*)d_in[3];
  const float* b1 = (const float*)d_in[4];
  const float* W2 = (const float*)d_in[5];
  const float* b2 = (const float*)d_in[6];
  const int* src  = (const int*)d_in[7];
  const int* dst  = (const int*)d_in[8];
  float* out = (float*)d_out;

  char* p = (char*)d_ws;
  auto alloc = [&](size_t bytes) -> char* {
    char* r = p;
    p += (bytes + 15) & ~(size_t)15;
    return r;
  };
  int* cin_p  = (int*)alloc((size_t)N * 64);   // padded: 8 bucket slots / 64B line
  int* cout_p = (int*)alloc((size_t)N * 64);
  int* cin_d  = (int*)alloc((size_t)N * 4);    // dense totals for scan
  int* cout_d = (int*)alloc((size_t)N * 4);
  int* offf = (int*)alloc((size_t)(N + 1) * 4);
  int* offb = (int*)alloc((size_t)(N + 1) * 4);
  uint4* basef = (uint4*)alloc((size_t)N * 16);  // packed 7x16b bucket prefixes
  uint4* baseb = (uint4*)alloc((size_t)N * 16);
  unsigned* rank_pk = (unsigned*)alloc((size_t)E * 4);   // rankf | rankb<<16
  unsigned* epf = (unsigned*)alloc((size_t)E * 4);       // (u<<16 | deg) payload
  unsigned* epb = (unsigned*)alloc((size_t)E * 4);
  unsigned* xbu = (unsigned*)alloc((size_t)N * 64 * 4);  // row-major bf16x2
  unsigned* fwdb = (unsigned*)alloc((size_t)N * 64 * 4);
  unsigned* bwdb = (unsigned*)alloc((size_t)N * 64 * 4);
  unsigned* Wth[3], *Wtl[3];
  for (int l = 0; l < 3; ++l) {
    Wth[l] = (unsigned*)alloc((size_t)128 * 192 * 4);
    Wtl[l] = (unsigned*)alloc((size_t)128 * 192 * 4);
  }
  int nbScan = (N + 1 + 2047) / 2048;
  int* partA = (int*)alloc((size_t)(nbScan + 1) * 4);
  int* partB = (int*)alloc((size_t)(nbScan + 1) * 4);

  hipMemsetAsync(cin_p, 0, (size_t)2 * N * 64, stream);  // cin_p+cout_p contiguous

  k_degrees<<<(E + 255) / 256, 256, 0, stream>>>(src, dst, cin_p, cout_p,
                                                 rank_pk, E);
  k_compact<<<(N + 255) / 256, 256, 0, stream>>>(cin_p, cout_p, cin_d, cout_d,
                                                 basef, baseb, N);
  k_scan_part<<<dim3(nbScan, 2), 256, 0, stream>>>(cin_d, cout_d, partA, partB, N);
  k_scan_tops<<<dim3(1, 2), 64, 0, stream>>>(partA, partB, nbScan);
  k_scan_out<<<dim3(nbScan, 2), 256, 0, stream>>>(cin_d, cout_d, partA, partB,
                                                  offf, offb, N);
  k_fill<<<(E + 255) / 256, 256, 0, stream>>>(src, dst, offf, offb, rank_pk,
                                              cout_d, cin_d, basef, baseb,
                                              epf, epb, E);
  k_wconv3<<<dim3((128 * 192 + 255) / 256, 3), 256, 0, stream>>>(
      W0, W1, W2, Wth[0], Wth[1], Wth[2], Wtl[0], Wtl[1], Wtl[2]);

  const float* bs[3] = {b0, b1, b2};
  int aggBlocks = (N + 15) / 16;          // 16 nodes/block (4 waves); dir = y
  int convBlocks = (N * 32 + 255) / 256;
  int gemmBlocks = (N + 127) / 128;

  k_conv<<<convBlocks, 256, 0, stream>>>(x, xbu, N);   // layer-0 input only
  for (int l = 0; l < 3; ++l) {
    k_agg6<<<dim3(aggBlocks, 2), 256, 0, stream>>>(
        (const uint4*)xbu, offf, epf, basef, offb, epb, baseb,
        (uint4*)fwdb, (uint4*)bwdb, N);
    if (l < 2) {
      k_gemm<<<gemmBlocks, 256, 0, stream>>>(xbu, fwdb, bwdb, Wth[l], Wtl[l],
                                             bs[l], (unsigned short*)xbu, nullptr, N);
    } else {
      k_gemm<<<gemmBlocks, 256, 0, stream>>>(xbu, fwdb, bwdb, Wth[l], Wtl[l],
                                             bs[l], nullptr, out, N);
    }
  }
}

// Round 6
// 471.020 us; speedup vs baseline: 1.0843x; 1.0843x over previous
//
#include <hip/hip_runtime.h>
#include <cstdint>

// ---------------------------------------------------------------------------
// DirGraphSAGE round 14: bucket-SORTED layout + r11's flat aggregation loop.
//  r13 evidence: bucket phasing cut FETCH 209->159 MB (locality mechanism
//  works) but barriers + ~2-edge segments collapsed MLP (rate 3.56->2.0 TB/s,
//  dur 66->80us). The locality does NOT need barriers: bucket-major edge
//  ordering inside each CSR list makes every thread walk x-slabs 0..7
//  monotonically, so concurrent waves naturally gather from the same ~1.6MB
//  L2-resident slab, drifting only with degree variance.
//  - k_degrees/k_compact/k_fill: unchanged from r13 (per-(node,bucket) ranks
//    in the padded 64B counter lines, packed 7x16b prefixes, sorted placement).
//  - k_agg6: reverted to r11's flat x4-unroll kernel (VGPR 28, occ ~69%,
//    proven 3.6 TB/s execution) - identical instruction stream, better layout.
//  - Everything else from r11: 4B payload (u<<16|deg), exact IEEE divide,
//    row-major bf16, split-W MFMA GEMM.
// ---------------------------------------------------------------------------

typedef __bf16 bf16x8 __attribute__((ext_vector_type(8)));
typedef float f32x4 __attribute__((ext_vector_type(4)));

__device__ __forceinline__ unsigned short f2bf(float f) {
  unsigned u = __float_as_uint(f);
  u += 0x7FFFu + ((u >> 16) & 1u);   // round-to-nearest-even
  return (unsigned short)(u >> 16);
}
__device__ __forceinline__ float bflo(unsigned u) { return __uint_as_float(u << 16); }
__device__ __forceinline__ float bfhi(unsigned u) { return __uint_as_float(u & 0xFFFF0000u); }

// prefix for bucket b (0..7) from packed uint4 (fields p1..p7); p0 = 0.
__device__ __forceinline__ unsigned prefield(uint4 v, int b) {
  if (b == 0) return 0u;
  int k = b - 1;  // 0..6
  unsigned w = (k < 2) ? v.x : (k < 4) ? v.y : (k < 6) ? v.z : v.w;
  return (k & 1) ? (w >> 16) : (w & 0xFFFFu);
}

// Padded counters: 16 ints (64B line) per node; slots 0..7 = per-bucket counts.
// Rank = arrival order within (node, source-bucket); packed 16|16 fwd|bwd.
__global__ __launch_bounds__(256) void k_degrees(const int* __restrict__ src,
                                                 const int* __restrict__ dst,
                                                 int* __restrict__ cin_p,
                                                 int* __restrict__ cout_p,
                                                 unsigned* __restrict__ rank_pk, int E) {
  int e = blockIdx.x * 256 + threadIdx.x;
  if (e >= E) return;
  int s = src[e], d = dst[e];
  int bf = (unsigned)s >> 13;   // bucket of gathered row for fwd list (by dst)
  int bb = (unsigned)d >> 13;   // bucket of gathered row for bwd list (by src)
  unsigned rf = (unsigned)atomicAdd(&cin_p[(size_t)d * 16 + bf], 1);
  unsigned rb = (unsigned)atomicAdd(&cout_p[(size_t)s * 16 + bb], 1);
  rank_pk[e] = (rf & 0xFFFFu) | (rb << 16);
}

// Per node: total degree (for scan) + packed 7x16b exclusive bucket prefixes.
__global__ __launch_bounds__(256) void k_compact(const int* __restrict__ cin_p,
                                                 const int* __restrict__ cout_p,
                                                 int* __restrict__ cin_d,
                                                 int* __restrict__ cout_d,
                                                 uint4* __restrict__ basef,
                                                 uint4* __restrict__ baseb, int n) {
  int i = blockIdx.x * 256 + threadIdx.x;
  if (i >= n) return;
  {
    const int* pf = &cin_p[(size_t)i * 16];
    int c0 = pf[0], c1 = pf[1], c2 = pf[2], c3 = pf[3];
    int c4 = pf[4], c5 = pf[5], c6 = pf[6], c7 = pf[7];
    unsigned run = c0;
    unsigned p1 = run; run += c1; unsigned p2 = run; run += c2;
    unsigned p3 = run; run += c3; unsigned p4 = run; run += c4;
    unsigned p5 = run; run += c5; unsigned p6 = run; run += c6;
    unsigned p7 = run; run += c7;
    cin_d[i] = (int)run;
    basef[i] = make_uint4(p1 | (p2 << 16), p3 | (p4 << 16), p5 | (p6 << 16), p7);
  }
  {
    const int* pf = &cout_p[(size_t)i * 16];
    int c0 = pf[0], c1 = pf[1], c2 = pf[2], c3 = pf[3];
    int c4 = pf[4], c5 = pf[5], c6 = pf[6], c7 = pf[7];
    unsigned run = c0;
    unsigned p1 = run; run += c1; unsigned p2 = run; run += c2;
    unsigned p3 = run; run += c3; unsigned p4 = run; run += c4;
    unsigned p5 = run; run += c5; unsigned p6 = run; run += c6;
    unsigned p7 = run; run += c7;
    cout_d[i] = (int)run;
    baseb[i] = make_uint4(p1 | (p2 << 16), p3 | (p4 << 16), p5 | (p6 << 16), p7);
  }
}

// --- 3-phase multi-block exclusive scan (CHUNK=2048/block, y-dim = which array)
__global__ __launch_bounds__(256) void k_scan_part(const int* __restrict__ cntA,
                                                   const int* __restrict__ cntB,
                                                   int* __restrict__ partA,
                                                   int* __restrict__ partB, int n) {
  const int* cnt = blockIdx.y ? cntB : cntA;
  int* part = blockIdx.y ? partB : partA;
  __shared__ int red[256];
  int t = threadIdx.x;
  int base = blockIdx.x * 2048 + t * 8;
  int s = 0;
#pragma unroll
  for (int i = 0; i < 8; ++i) {
    int idx = base + i;
    if (idx < n) s += cnt[idx];
  }
  red[t] = s;
  __syncthreads();
  for (int o = 128; o > 0; o >>= 1) {
    if (t < o) red[t] += red[t + o];
    __syncthreads();
  }
  if (t == 0) part[blockIdx.x] = red[0];
}

__global__ __launch_bounds__(64) void k_scan_tops(int* __restrict__ partA,
                                                  int* __restrict__ partB, int nb) {
  int* part = blockIdx.y ? partB : partA;
  if (threadIdx.x == 0) {
    int run = 0;
    for (int i = 0; i < nb; ++i) { int v = part[i]; part[i] = run; run += v; }
  }
}

__global__ __launch_bounds__(256) void k_scan_out(const int* __restrict__ cntA,
                                                  const int* __restrict__ cntB,
                                                  const int* __restrict__ partA,
                                                  const int* __restrict__ partB,
                                                  int* __restrict__ offA,
                                                  int* __restrict__ offB, int n) {
  const int* cnt = blockIdx.y ? cntB : cntA;
  const int* part = blockIdx.y ? partB : partA;
  int* off = blockIdx.y ? offB : offA;
  __shared__ int ts[256];
  int t = threadIdx.x;
  int base = blockIdx.x * 2048 + t * 8;
  int v[8];
  int s = 0;
#pragma unroll
  for (int i = 0; i < 8; ++i) {
    int idx = base + i;
    int c = (idx < n) ? cnt[idx] : 0;
    v[i] = s;          // exclusive prefix within thread
    s += c;
  }
  ts[t] = s;
  __syncthreads();
  for (int o = 1; o < 256; o <<= 1) {
    int val = (t >= o) ? ts[t - o] : 0;
    __syncthreads();
    ts[t] += val;
    __syncthreads();
  }
  int blockbase = part[blockIdx.x] + (t ? ts[t - 1] : 0);
#pragma unroll
  for (int i = 0; i < 8; ++i) {
    int idx = base + i;
    if (idx <= n) off[idx] = blockbase + v[i];   // idx==n writes the total
  }
}

// Atomic-free fill; pos = off[node] + bucketPrefix + rankWithinBucket.
__global__ __launch_bounds__(256) void k_fill(const int* __restrict__ src,
                                              const int* __restrict__ dst,
                                              const int* __restrict__ offf,
                                              const int* __restrict__ offb,
                                              const unsigned* __restrict__ rank_pk,
                                              const int* __restrict__ cout_d,
                                              const int* __restrict__ cin_d,
                                              const uint4* __restrict__ basef,
                                              const uint4* __restrict__ baseb,
                                              unsigned* __restrict__ epf,
                                              unsigned* __restrict__ epb, int E) {
  int e = blockIdx.x * 256 + threadIdx.x;
  if (e >= E) return;
  int s = src[e], d = dst[e];
  unsigned rp = rank_pk[e];
  int rf = (int)(rp & 0xFFFFu), rb = (int)(rp >> 16);
  int bf = (unsigned)s >> 13, bb = (unsigned)d >> 13;
  unsigned co = (unsigned)cout_d[s]; if (co > 65535u) co = 65535u;
  unsigned ci = (unsigned)cin_d[d];  if (ci > 65535u) ci = 65535u;
  epf[offf[d] + (int)prefield(basef[d], bf) + rf] = ((unsigned)s << 16) | co;
  epb[offb[s] + (int)prefield(baseb[s], bb) + rb] = ((unsigned)d << 16) | ci;
}

// x (fp32, N x 128) -> xbu row-major packed bf16x2 (32 uint2 per row)
__global__ __launch_bounds__(256) void k_conv(const float* __restrict__ x,
                                              unsigned* __restrict__ xbu, int n) {
  int idx = blockIdx.x * 256 + threadIdx.x;  // over n*32 float4s
  if (idx >= n * 32) return;
  float4 xv = ((const float4*)x)[idx];
  unsigned u0 = (unsigned)f2bf(xv.x) | ((unsigned)f2bf(xv.y) << 16);
  unsigned u1 = (unsigned)f2bf(xv.z) | ((unsigned)f2bf(xv.w) << 16);
  ((uint2*)xbu)[idx] = make_uint2(u0, u1);
}

// W (fp32 384x128) -> Wt_hi, Wt_lo (bf16, 128x384, transposed, packed x2)
__global__ __launch_bounds__(256) void k_wconv3(
    const float* __restrict__ Wa, const float* __restrict__ Wb,
    const float* __restrict__ Wc,
    unsigned* __restrict__ Ha, unsigned* __restrict__ Hb, unsigned* __restrict__ Hc,
    unsigned* __restrict__ La, unsigned* __restrict__ Lb, unsigned* __restrict__ Lc) {
  const float* W = (blockIdx.y == 0) ? Wa : ((blockIdx.y == 1) ? Wb : Wc);
  unsigned* Wth = (blockIdx.y == 0) ? Ha : ((blockIdx.y == 1) ? Hb : Hc);
  unsigned* Wtl = (blockIdx.y == 0) ? La : ((blockIdx.y == 1) ? Lb : Lc);
  int t = blockIdx.x * 256 + threadIdx.x;   // 128*192 threads; t = j*192 + k2
  if (t >= 128 * 192) return;
  int j = t / 192, k2 = t - j * 192;
  int k = k2 * 2;
  float w0 = W[k * 128 + j], w1 = W[(k + 1) * 128 + j];
  unsigned short h0 = f2bf(w0), h1 = f2bf(w1);
  float l0 = w0 - __uint_as_float((unsigned)h0 << 16);
  float l1 = w1 - __uint_as_float((unsigned)h1 << 16);
  Wth[t] = (unsigned)h0 | ((unsigned)h1 << 16);
  Wtl[t] = (unsigned)f2bf(l0) | ((unsigned)f2bf(l1) << 16);
}

// Single-pass row-major aggregation (r11's flat kernel). 16 lanes/node,
// 4 nodes/wave, x4 unroll. Edge lists are bucket-major (sorted by gathered-id
// slab): all concurrent waves walk x-slabs 0..7 monotonically -> the active
// slab tends to stay L2-resident without any barriers or loop overhead.
__global__ __launch_bounds__(256) void k_agg6(const uint4* __restrict__ xb,
                                              const int* __restrict__ offA,
                                              const unsigned* __restrict__ epA,
                                              const int* __restrict__ offB,
                                              const unsigned* __restrict__ epB,
                                              uint4* __restrict__ outA,
                                              uint4* __restrict__ outB, int n) {
  int lane = threadIdx.x & 63;
  int gi = lane >> 4, c = lane & 15;     // node-in-wave, uint4 column
  int node = ((blockIdx.x * 256 + threadIdx.x) >> 6) * 4 + gi;
  if (node >= n) return;
  const int* off = blockIdx.y ? offB : offA;
  const unsigned* ep = blockIdx.y ? epB : epA;
  uint4* out = blockIdx.y ? outB : outA;

  int i = off[node], end = off[node + 1];
  float acc[8];
#pragma unroll
  for (int k = 0; k < 8; ++k) acc[k] = 0.f;

#define AGG_BODY(r_, w_)                                                      \
  acc[0] = fmaf(bflo(r_.x), w_, acc[0]); acc[1] = fmaf(bfhi(r_.x), w_, acc[1]); \
  acc[2] = fmaf(bflo(r_.y), w_, acc[2]); acc[3] = fmaf(bfhi(r_.y), w_, acc[3]); \
  acc[4] = fmaf(bflo(r_.z), w_, acc[4]); acc[5] = fmaf(bfhi(r_.z), w_, acc[5]); \
  acc[6] = fmaf(bflo(r_.w), w_, acc[6]); acc[7] = fmaf(bfhi(r_.w), w_, acc[7]);

  for (; i + 3 < end; i += 4) {
    unsigned e0 = ep[i], e1 = ep[i + 1], e2 = ep[i + 2], e3 = ep[i + 3];
    uint4 r0 = xb[(size_t)(e0 >> 16) * 16 + c];
    uint4 r1 = xb[(size_t)(e1 >> 16) * 16 + c];
    uint4 r2 = xb[(size_t)(e2 >> 16) * 16 + c];
    uint4 r3 = xb[(size_t)(e3 >> 16) * 16 + c];
    float w0 = 1.0f / (float)(e0 & 0xFFFFu);   // IEEE div: bit-exact vs table
    float w1 = 1.0f / (float)(e1 & 0xFFFFu);
    float w2 = 1.0f / (float)(e2 & 0xFFFFu);
    float w3 = 1.0f / (float)(e3 & 0xFFFFu);
    AGG_BODY(r0, w0)
    AGG_BODY(r1, w1)
    AGG_BODY(r2, w2)
    AGG_BODY(r3, w3)
  }
  for (; i < end; ++i) {
    unsigned e0 = ep[i];
    uint4 r0 = xb[(size_t)(e0 >> 16) * 16 + c];
    float w0 = 1.0f / (float)(e0 & 0xFFFFu);
    AGG_BODY(r0, w0)
  }
#undef AGG_BODY

  uint4 o;
  o.x = (unsigned)f2bf(acc[0]) | ((unsigned)f2bf(acc[1]) << 16);
  o.y = (unsigned)f2bf(acc[2]) | ((unsigned)f2bf(acc[3]) << 16);
  o.z = (unsigned)f2bf(acc[4]) | ((unsigned)f2bf(acc[5]) << 16);
  o.w = (unsigned)f2bf(acc[6]) | ((unsigned)f2bf(acc[7]) << 16);
  out[(size_t)node * 16 + c] = o;
}

// MFMA GEMM: h = bias + [xbu|fwdb|bwdb][v,:] @ (W_hi + W_lo)   (row-major A)
// If outb: write bf16(relu(h)) row-major (next layer's xbu). Else fp32 outf.
__global__ __launch_bounds__(256) void k_gemm(const unsigned* __restrict__ xbu,
                                              const unsigned* __restrict__ fwdb,
                                              const unsigned* __restrict__ bwdb,
                                              const unsigned* __restrict__ Wth,
                                              const unsigned* __restrict__ Wtl,
                                              const float* __restrict__ bias,
                                              unsigned short* __restrict__ outb,
                                              float* __restrict__ outf, int n) {
  __shared__ uint4 sA[512];    // 8 KB: A chunk, frag order [mt][q][m]
  __shared__ uint4 sWh[512];   // 8 KB
  __shared__ uint4 sWl[512];   // 8 KB
  int tid = threadIdx.x;
  int bm0 = blockIdx.x * 128;
  int w = tid >> 6, lane = tid & 63;

  f32x4 acc[2][8];
#pragma unroll
  for (int mt = 0; mt < 2; ++mt)
#pragma unroll
    for (int nt = 0; nt < 8; ++nt) acc[mt][nt] = (f32x4){0.f, 0.f, 0.f, 0.f};

  const uint4* Wh4 = (const uint4*)Wth;   // row j: 48 uint4 (384 bf16)
  const uint4* Wl4 = (const uint4*)Wtl;

  for (int kc = 0; kc < 12; ++kc) {
    const uint4* src4 = (const uint4*)((kc < 4) ? xbu : ((kc < 8) ? fwdb : bwdb));
    int ko = (kc & 3) * 4;   // uint4 offset within row (16 uint4 = 128 bf16)
    __syncthreads();
#pragma unroll
    for (int p = 0; p < 2; ++p) {
      int f = tid + p * 256;          // 0..511
      int r = f >> 2, q = f & 3;      // r: row/col-of-W, q: k-quad
      int slot = (r >> 4) * 64 + q * 16 + (r & 15);
      int v = bm0 + r;
      uint4 val = make_uint4(0u, 0u, 0u, 0u);
      if (v < n) val = src4[(size_t)v * 16 + ko + q];
      sA[slot] = val;
      sWh[slot] = Wh4[(size_t)r * 48 + kc * 4 + q];
      sWl[slot] = Wl4[(size_t)r * 48 + kc * 4 + q];
    }
    __syncthreads();
    bf16x8 a0 = ((const bf16x8*)sA)[(2 * w) * 64 + lane];
    bf16x8 a1 = ((const bf16x8*)sA)[(2 * w + 1) * 64 + lane];
#pragma unroll
    for (int nt = 0; nt < 8; ++nt) {
      bf16x8 bh = ((const bf16x8*)sWh)[nt * 64 + lane];
      bf16x8 bl = ((const bf16x8*)sWl)[nt * 64 + lane];
      acc[0][nt] = __builtin_amdgcn_mfma_f32_16x16x32_bf16(a0, bh, acc[0][nt], 0, 0, 0);
      acc[0][nt] = __builtin_amdgcn_mfma_f32_16x16x32_bf16(a0, bl, acc[0][nt], 0, 0, 0);
      acc[1][nt] = __builtin_amdgcn_mfma_f32_16x16x32_bf16(a1, bh, acc[1][nt], 0, 0, 0);
      acc[1][nt] = __builtin_amdgcn_mfma_f32_16x16x32_bf16(a1, bl, acc[1][nt], 0, 0, 0);
    }
  }

  // Epilogue. C layout: col = lane&15, row = (lane>>4)*4 + reg  (m89-verified)
  int col = lane & 15;
  float bv[8];
#pragma unroll
  for (int nt = 0; nt < 8; ++nt) bv[nt] = bias[nt * 16 + col];
#pragma unroll
  for (int mt = 0; mt < 2; ++mt) {
    int rowbase = bm0 + w * 32 + mt * 16 + (lane >> 4) * 4;
#pragma unroll
    for (int reg = 0; reg < 4; ++reg) {
      int row = rowbase + reg;
      if (row >= n) continue;
      if (outb) {
#pragma unroll
        for (int nt = 0; nt < 8; ++nt) {
          float t = fmaxf(acc[mt][nt][reg] + bv[nt], 0.f);   // relu layers
          outb[(size_t)row * 128 + nt * 16 + col] = f2bf(t);
        }
      } else {
#pragma unroll
        for (int nt = 0; nt < 8; ++nt) {
          float t = acc[mt][nt][reg] + bv[nt];
          outf[(size_t)row * 128 + nt * 16 + col] = t;
        }
      }
    }
  }
}

extern "C" void kernel_launch(void* const* d_in, const int* in_sizes, int n_in,
                              void* d_out, int out_size, void* d_ws, size_t ws_size,
                              hipStream_t stream) {
  const int D = 128;
  const int N = in_sizes[0] / D;
  const int E = in_sizes[7];

  const float* x  = (const float*)d_in[0];
  const float* W0 = (const float*)d_in[1];
  const float* b0 = (const float*)d_in[2];
  const float* W1 = (const float*)d_in[3];
  const float* b1 = (const float*)d_in[4];
  const float* W2 = (const float*)d_in[5];
  const float* b2 = (const float*)d_in[6];
  const int* src  = (const int*)d_in[7];
  const int* dst  = (const int*)d_in[8];
  float* out = (float*)d_out;

  char* p = (char*)d_ws;
  auto alloc = [&](size_t bytes) -> char* {
    char* r = p;
    p += (bytes + 15) & ~(size_t)15;
    return r;
  };
  int* cin_p  = (int*)alloc((size_t)N * 64);   // padded: 8 bucket slots / 64B line
  int* cout_p = (int*)alloc((size_t)N * 64);
  int* cin_d  = (int*)alloc((size_t)N * 4);    // dense totals for scan
  int* cout_d = (int*)alloc((size_t)N * 4);
  int* offf = (int*)alloc((size_t)(N + 1) * 4);
  int* offb = (int*)alloc((size_t)(N + 1) * 4);
  uint4* basef = (uint4*)alloc((size_t)N * 16);  // packed 7x16b bucket prefixes
  uint4* baseb = (uint4*)alloc((size_t)N * 16);
  unsigned* rank_pk = (unsigned*)alloc((size_t)E * 4);   // rankf | rankb<<16
  unsigned* epf = (unsigned*)alloc((size_t)E * 4);       // (u<<16 | deg) payload
  unsigned* epb = (unsigned*)alloc((size_t)E * 4);
  unsigned* xbu = (unsigned*)alloc((size_t)N * 64 * 4);  // row-major bf16x2
  unsigned* fwdb = (unsigned*)alloc((size_t)N * 64 * 4);
  unsigned* bwdb = (unsigned*)alloc((size_t)N * 64 * 4);
  unsigned* Wth[3], *Wtl[3];
  for (int l = 0; l < 3; ++l) {
    Wth[l] = (unsigned*)alloc((size_t)128 * 192 * 4);
    Wtl[l] = (unsigned*)alloc((size_t)128 * 192 * 4);
  }
  int nbScan = (N + 1 + 2047) / 2048;
  int* partA = (int*)alloc((size_t)(nbScan + 1) * 4);
  int* partB = (int*)alloc((size_t)(nbScan + 1) * 4);

  hipMemsetAsync(cin_p, 0, (size_t)2 * N * 64, stream);  // cin_p+cout_p contiguous

  k_degrees<<<(E + 255) / 256, 256, 0, stream>>>(src, dst, cin_p, cout_p,
                                                 rank_pk, E);
  k_compact<<<(N + 255) / 256, 256, 0, stream>>>(cin_p, cout_p, cin_d, cout_d,
                                                 basef, baseb, N);
  k_scan_part<<<dim3(nbScan, 2), 256, 0, stream>>>(cin_d, cout_d, partA, partB, N);
  k_scan_tops<<<dim3(1, 2), 64, 0, stream>>>(partA, partB, nbScan);
  k_scan_out<<<dim3(nbScan, 2), 256, 0, stream>>>(cin_d, cout_d, partA, partB,
                                                  offf, offb, N);
  k_fill<<<(E + 255) / 256, 256, 0, stream>>>(src, dst, offf, offb, rank_pk,
                                              cout_d, cin_d, basef, baseb,
                                              epf, epb, E);
  k_wconv3<<<dim3((128 * 192 + 255) / 256, 3), 256, 0, stream>>>(
      W0, W1, W2, Wth[0], Wth[1], Wth[2], Wtl[0], Wtl[1], Wtl[2]);

  const float* bs[3] = {b0, b1, b2};
  int aggBlocks = (N + 15) / 16;          // 16 nodes/block (4 waves); dir = y
  int convBlocks = (N * 32 + 255) / 256;
  int gemmBlocks = (N + 127) / 128;

  k_conv<<<convBlocks, 256, 0, stream>>>(x, xbu, N);   // layer-0 input only
  for (int l = 0; l < 3; ++l) {
    k_agg6<<<dim3(aggBlocks, 2), 256, 0, stream>>>(
        (const uint4*)xbu, offf, epf, offb, epb,
        (uint4*)fwdb, (uint4*)bwdb, N);
    if (l < 2) {
      k_gemm<<<gemmBlocks, 256, 0, stream>>>(xbu, fwdb, bwdb, Wth[l], Wtl[l],
                                             bs[l], (unsigned short*)xbu, nullptr, N);
    } else {
      k_gemm<<<gemmBlocks, 256, 0, stream>>>(xbu, fwdb, bwdb, Wth[l], Wtl[l],
                                             bs[l], nullptr, out, N);
    }
  }
}